// Round 1
// 554.172 us; speedup vs baseline: 1.0007x; 1.0007x over previous
//
#include <hip/hip_runtime.h>
#include <math.h>

// Fully fused SNN forward (linearity collapse verified R1-R3, absmax 4.8e-7).
// R5: occupancy fix. R4 analysis: VALUBusy 59% x 263us = 155us ~= the fp32
// VALU issue floor (v_pk_fma_f32 is half-rate/inst on gfx950: FP32 peak
// 157 TF == scalar v_fma full rate, so pk compresses insts, not cycles).
// The 41% idle is lgkmcnt(0) drains (out-of-order s_load returns conflated
// with ds_read) unhidden at 2 waves/SIMD (grid 512 = 2 blocks/CU, occ 19%).
// Change: 1 batch/block, 1024 blocks, thread tile 4x25 -> 2x25, LDS
// 50.7 -> 19.2 KB, __launch_bounds__(256,4) -> 4 blocks/CU = 4 waves/SIMD.
// Inner loop (SMEM s_load weights + v_pk_fma) kept verbatim from R4.

#define NSTEPS 100
#define NHID 100
#define KDIM 784
#define BKT 16        // 784 = 49 * 16 exact
#define NROWS 128     // padded timestep rows per batch (100 real)
#define NOUT 10

typedef float v2f __attribute__((ext_vector_type(2)));

// ---- tiny transpose: Wt[k][32*cg + i] = W1[25*cg + i][k], pad i>=25 with 0
__global__ __launch_bounds__(256)
void wt_transpose(const float* __restrict__ W1, float* __restrict__ Wt) {
  const int idx = blockIdx.x * 256 + threadIdx.x;   // 784*128 entries
  if (idx >= KDIM * 128) return;
  const int k = idx >> 7, s = idx & 127, cg = s >> 5, i = s & 31;
  const int j = 25 * cg + i;
  Wt[idx] = (i < 25) ? W1[(size_t)j * KDIM + k] : 0.0f;
}

__global__ __launch_bounds__(256, 4)
void snn_fused4(const float* __restrict__ X, const float* __restrict__ Wt,
                const float* __restrict__ wsyn1p, const float* __restrict__ b1,
                const float* __restrict__ wsyn2p, const float* __restrict__ W2,
                const float* __restrict__ b2, float* __restrict__ out) {
  __shared__ float Xs[BKT][NROWS];   // 8.0 KB: k-major X tile (1 batch)
  __shared__ float Cs[25][106];      // 10.6 KB scan chunk, stride 106
  __shared__ float zsh[NHID];

  const int tid = threadIdx.x;
  const int l   = tid & 63;
  const int cg  = __builtin_amdgcn_readfirstlane(tid >> 6);  // wave col group
  const long b  = blockIdx.x;

  // staging identity: 2 threads per timestep row, 8 consecutive k each
  const int row  = tid >> 1;                       // 0..127 (t, clamped)
  const int half = tid & 1;
  const int st   = (row < NSTEPS) ? row : (NSTEPS - 1);
  const float* __restrict__ Xrow =
      X + ((size_t)b * NSTEPS + st) * KDIM + 8 * half;

  v2f  acc2[2][12];                  // rows 2l, 2l+1; col pairs 0..23
  float accs[2];                     // col 24
#pragma unroll
  for (int i = 0; i < 2; ++i) {
    accs[i] = 0.0f;
#pragma unroll
    for (int c = 0; c < 12; ++c) acc2[i][c] = (v2f){0.0f, 0.0f};
  }

  float4 pf0 = *(const float4*)(Xrow);
  float4 pf1 = *(const float4*)(Xrow + 4);

  const float* __restrict__ wgrp = Wt + 32 * cg;   // uniform -> SMEM path

  for (int kt = 0; kt < KDIM; kt += BKT) {
    __syncthreads();                 // previous tile's LDS reads complete
    {
      const int k0 = 8 * half;
      Xs[k0 + 0][row] = pf0.x;
      Xs[k0 + 1][row] = pf0.y;
      Xs[k0 + 2][row] = pf0.z;
      Xs[k0 + 3][row] = pf0.w;
      Xs[k0 + 4][row] = pf1.x;
      Xs[k0 + 5][row] = pf1.y;
      Xs[k0 + 6][row] = pf1.z;
      Xs[k0 + 7][row] = pf1.w;
    }
    __syncthreads();
    if (kt + BKT < KDIM) {
      pf0 = *(const float4*)(Xrow + kt + BKT);
      pf1 = *(const float4*)(Xrow + kt + BKT + 4);
    }

#pragma unroll 4
    for (int k = 0; k < BKT; ++k) {
      const v2f xv = *(const v2f*)&Xs[k][2 * l];
      const float* __restrict__ wk = wgrp + (size_t)(kt + k) * 128;  // uniform
      float w[26];
#pragma unroll
      for (int i2 = 0; i2 < 13; ++i2)
        *(v2f*)(w + 2 * i2) = *(const v2f*)(wk + 2 * i2);  // s_load pairs

      const v2f xd0 = {xv.x, xv.x};
      const v2f xd1 = {xv.y, xv.y};
#pragma unroll
      for (int c2 = 0; c2 < 12; ++c2) {
        const v2f wv = *(const v2f*)(w + 2 * c2);
        acc2[0][c2] = __builtin_elementwise_fma(xd0, wv, acc2[0][c2]);
        acc2[1][c2] = __builtin_elementwise_fma(xd1, wv, acc2[1][c2]);
      }
      const float w24 = w[24];
      accs[0] = fmaf(xv.x, w24, accs[0]);
      accs[1] = fmaf(xv.y, w24, accs[1]);
    }
  }

  // ---- fused scan epilogue: 4 chunks of 25 timesteps (1 batch)
  const float inv1 = 1.f / (1.f + expf(-wsyn1p[0]));
  const float inv2 = 1.f / (1.f + expf(-wsyn2p[0]));
  const float bj = (tid < NHID) ? b1[tid] : 0.f;
  float S = 0.f, v1 = 0.f, s2 = 0.f, z = 0.f;
  float at = 0x1p-100f;              // 2^(t-100)

  for (int q = 0; q < 4; ++q) {
    __syncthreads();                 // previous chunk's reads complete
#pragma unroll
    for (int i = 0; i < 2; ++i) {
      const int r  = 2 * l + i;      // timestep row this acc holds
      const int tt = r - 25 * q;
      if (tt >= 0 && tt < 25 && r < NSTEPS) {
        float* crow = &Cs[tt][25 * cg];
#pragma unroll
        for (int c2 = 0; c2 < 12; ++c2) {
          crow[2 * c2 + 0] = acc2[i][c2].x;
          crow[2 * c2 + 1] = acc2[i][c2].y;
        }
        crow[24] = accs[i];
      }
    }
    __syncthreads();
    if (tid < NHID) {
#pragma unroll
      for (int tt = 0; tt < 25; ++tt) {
        const float u = Cs[tt][tid];
        S = S - S * inv1 + u;             // SynapseFilter 1 (h-space)
        const float h = S + bj;
        v1 = v1 + (h - v1) * 0.5f;        // LIF1, tau=2
        const float sp = (v1 >= 1.0f) ? 1.0f : 0.0f;
        v1 = v1 * (1.0f - sp);            // hard reset
        s2 = s2 - s2 * inv2 + sp;         // SynapseFilter 2
        z  = fmaf(at, s2, z);
        at *= 2.0f;
      }
    }
  }

  if (tid < NHID) zsh[tid] = z;
  __syncthreads();

  if (tid < NOUT) {
    float a = b2[tid];
    const float* __restrict__ wrow = W2 + tid * NHID;
#pragma unroll
    for (int jj = 0; jj < NHID; ++jj) a = fmaf(zsh[jj], wrow[jj], a);
    out[b * NOUT + tid] = a;
  }
}

extern "C" void kernel_launch(void* const* d_in, const int* in_sizes, int n_in,
                              void* d_out, int out_size, void* d_ws, size_t ws_size,
                              hipStream_t stream) {
  const float* x     = (const float*)d_in[0];
  const float* wsyn1 = (const float*)d_in[1];
  const float* W1    = (const float*)d_in[2];
  const float* b1    = (const float*)d_in[3];
  const float* wsyn2 = (const float*)d_in[4];
  const float* W2    = (const float*)d_in[5];
  const float* b2    = (const float*)d_in[6];
  float* out = (float*)d_out;
  float* Wt  = (float*)d_ws;   // 784 x 128 fp32 = 401 KB

  wt_transpose<<<dim3((KDIM * 128 + 255) / 256), dim3(256), 0, stream>>>(W1, Wt);
  snn_fused4<<<dim3(1024), dim3(256), 0, stream>>>(x, Wt, wsyn1, b1, wsyn2, W2,
                                                   b2, out);
}